// Round 5
// baseline (1378.439 us; speedup 1.0000x reference)
//
#include <hip/hip_runtime.h>

// N=65536 vectors (16x4096), D=64, K=1024, all fp32.
// d_out (f32 flat concat): quantized[N*D], one-hot[N*K], loss, cb_loss, commit_loss.
// Argmin replicates the numpy-f32 reference BIT-EXACTLY (verified in R4):
//   d[n,k] = fl32( fl32(sx[n] + se[k]) - 2*fl32(dot64[n,k]) )
// sx = numpy pairwise-tree in f32; se/dot = fp64-exact rounded once; strict <
// with ascending k = np.argmin first-index tie-break (ties DO occur).
#define NVEC 65536
#define KCB  1024
#define DIM  64
#define ENC_OFF   ((size_t)NVEC * DIM)            // 4194304
#define LOSS_OFF  (ENC_OFF + (size_t)NVEC * KCB)  // 71303168

// ws layout (fast path): [0, 512K) fp64 codebook; [512K, 512K+4K) f32 norms
#define WS_E64_BOFF 0
#define WS_SE_BOFF  (KCB * DIM * 8)               // 524288
#define WS_NEED     (WS_SE_BOFF + KCB * 4)        // 528384

__global__ void vq_zero(float* __restrict__ loss3) {
    if (threadIdx.x < 3) loss3[threadIdx.x] = 0.0f;
}

// ---- fast path: pre-convert codebook to fp64 + f32 norms (bit-exact tree) ----
__global__ __launch_bounds__(256) void vq_cvt(const float* __restrict__ emb,
                                              double* __restrict__ emb64,
                                              float* __restrict__ se) {
    int g = blockIdx.x * 256 + threadIdx.x;     // 65536 threads
    emb64[g] = (double)emb[g];                  // coalesced f32->f64 copy
    if (g < KCB) {
        const float4* er = (const float4*)(emb + (size_t)g * DIM);
        double s0 = 0.0, s1 = 0.0, s2 = 0.0, s3 = 0.0;  // same chains as R4
#pragma unroll
        for (int i = 0; i < 16; i++) {
            float4 e = er[i];
            s0 = fma((double)e.x, (double)e.x, s0);
            s1 = fma((double)e.y, (double)e.y, s1);
            s2 = fma((double)e.z, (double)e.z, s2);
            s3 = fma((double)e.w, (double)e.w, s3);
        }
        se[g] = (float)((s0 + s1) + (s2 + s3));
    }
}

// Split-K main: block = 64 vectors x 4 code-quarters (wave q scans codes
// [256q, 256q+256)). e-rows are wave-uniform fp64 reads (scalarizable);
// x stays f32 in regs, converted at use (keeps VGPRs low for occupancy).
__global__ __launch_bounds__(256) void vq_main5(const float* __restrict__ x,
                                                const float* __restrict__ emb,
                                                const double* __restrict__ emb64,
                                                const float* __restrict__ se,
                                                float* __restrict__ outq,
                                                float* __restrict__ enc,
                                                float* __restrict__ lossacc) {
    __shared__ float sdq[4][64];
    __shared__ int   siq[4][64];
    __shared__ int   sidx[64];
    __shared__ float red[4];

    const int lane = threadIdx.x & 63;
    const int q = threadIdx.x >> 6;
    const int n = blockIdx.x * 64 + lane;

    const float4* xr = (const float4*)(x + (size_t)n * DIM);
    float xf[64];
#pragma unroll
    for (int i = 0; i < 16; i++) ((float4*)xf)[i] = xr[i];

    // sx = numpy pairwise_sum(x_i^2, n=64): 8 strided f32 chains + fixed tree.
    // __fmul_rn/__fadd_rn block FMA contraction (the rounding is load-bearing).
    float r[8];
#pragma unroll
    for (int j = 0; j < 8; j++) r[j] = __fmul_rn(xf[j], xf[j]);
#pragma unroll
    for (int b = 1; b < 8; b++)
#pragma unroll
        for (int j = 0; j < 8; j++)
            r[j] = __fadd_rn(r[j], __fmul_rn(xf[8 * b + j], xf[8 * b + j]));
    float sx = __fadd_rn(
        __fadd_rn(__fadd_rn(r[0], r[1]), __fadd_rn(r[2], r[3])),
        __fadd_rn(__fadd_rn(r[4], r[5]), __fadd_rn(r[6], r[7])));

    float best = 3.4e38f;
    int bidx = q * 256;
    for (int kk = 0; kk < 256; kk++) {
        int k = q * 256 + kk;
        const double* er = emb64 + (size_t)k * DIM;  // wave-uniform address
        double s0 = 0.0, s1 = 0.0, s2 = 0.0, s3 = 0.0;  // chains == R4 exactly
#pragma unroll
        for (int i = 0; i < 16; i++) {
            s0 = fma(er[4 * i + 0], (double)xf[4 * i + 0], s0);
            s1 = fma(er[4 * i + 1], (double)xf[4 * i + 1], s1);
            s2 = fma(er[4 * i + 2], (double)xf[4 * i + 2], s2);
            s3 = fma(er[4 * i + 3], (double)xf[4 * i + 3], s3);
        }
        float dot32 = (float)((s0 + s1) + (s2 + s3));
        float t1 = __fadd_rn(sx, se[k]);
        float d = __fsub_rn(t1, __fmul_rn(2.0f, dot32));
        if (d < best) { best = d; bidx = k; }  // strict < == first-index tie
    }
    sdq[q][lane] = best;
    siq[q][lane] = bidx;
    __syncthreads();

    // merge quarters (ascending q preserves global first-index tie-break)
    if (threadIdx.x < 64) {
        float b = sdq[0][lane];
        int bi = siq[0][lane];
#pragma unroll
        for (int qq = 1; qq < 4; qq++) {
            float dq = sdq[qq][lane];
            if (dq < b) { b = dq; bi = siq[qq][lane]; }
        }
        sidx[lane] = bi;
    }
    __syncthreads();

    // cooperative epilogue: quantized write (coalesced) + loss partials.
    // thread -> (vec = t>>2, 16-float chunk = t&3)
    {
        int vec = threadIdx.x >> 2, ch = threadIdx.x & 3;
        int id = sidx[vec];
        const float4* ebp = (const float4*)(emb + (size_t)id * DIM) + ch * 4;
        const float4* xp = (const float4*)(x + (size_t)(blockIdx.x * 64 + vec) * DIM) + ch * 4;
        float4* op = (float4*)(outq + (size_t)(blockIdx.x * 64 + vec) * DIM) + ch * 4;
        float sq = 0.0f;
#pragma unroll
        for (int i = 0; i < 4; i++) {
            float4 e = ebp[i];
            float4 xv = xp[i];
            float a0 = e.x - xv.x, a1 = e.y - xv.y;
            float a2 = e.z - xv.z, a3 = e.w - xv.w;
            sq += a0 * a0 + a1 * a1 + a2 * a2 + a3 * a3;
            op[i] = e;
        }
        for (int off = 32; off; off >>= 1) sq += __shfl_down(sq, off);
        if ((threadIdx.x & 63) == 0) red[threadIdx.x >> 6] = sq;
        __syncthreads();
        if (threadIdx.x == 0) atomicAdd(lossacc, red[0] + red[1] + red[2] + red[3]);
    }

    // one-hot slab: 64 rows x 256 float4, fully coalesced
    float4* encb = (float4*)enc + (size_t)blockIdx.x * 64 * 256;
    for (int t = threadIdx.x; t < 64 * 256; t += 256) {
        int id = sidx[t >> 8];
        int j = (t & 255) << 2;
        float4 v;
        v.x = (id == j + 0) ? 1.0f : 0.0f;
        v.y = (id == j + 1) ? 1.0f : 0.0f;
        v.z = (id == j + 2) ? 1.0f : 0.0f;
        v.w = (id == j + 3) ? 1.0f : 0.0f;
        encb[t] = v;
    }
}

// ---- fallback (proven R4 kernel) if ws is too small for the fp64 codebook ----
__global__ __launch_bounds__(256) void vq_main_fb(const float* __restrict__ x,
                                                  const float* __restrict__ emb,
                                                  float* __restrict__ outq,
                                                  float* __restrict__ enc,
                                                  float* __restrict__ lossacc) {
    __shared__ float se[KCB];
    __shared__ int sidx[256];
    __shared__ float red[4];
    for (int k = threadIdx.x; k < KCB; k += 256) {
        const float4* er = (const float4*)(emb + (size_t)k * DIM);
        double s0 = 0.0, s1 = 0.0, s2 = 0.0, s3 = 0.0;
#pragma unroll
        for (int i = 0; i < 16; i++) {
            float4 e = er[i];
            s0 = fma((double)e.x, (double)e.x, s0);
            s1 = fma((double)e.y, (double)e.y, s1);
            s2 = fma((double)e.z, (double)e.z, s2);
            s3 = fma((double)e.w, (double)e.w, s3);
        }
        se[k] = (float)((s0 + s1) + (s2 + s3));
    }
    __syncthreads();
    const int n = blockIdx.x * 256 + threadIdx.x;
    const float4* xr = (const float4*)(x + (size_t)n * DIM);
    float xf[64];
#pragma unroll
    for (int i = 0; i < 16; i++) ((float4*)xf)[i] = xr[i];
    float r[8];
#pragma unroll
    for (int j = 0; j < 8; j++) r[j] = __fmul_rn(xf[j], xf[j]);
#pragma unroll
    for (int b = 1; b < 8; b++)
#pragma unroll
        for (int j = 0; j < 8; j++)
            r[j] = __fadd_rn(r[j], __fmul_rn(xf[8 * b + j], xf[8 * b + j]));
    float sx = __fadd_rn(
        __fadd_rn(__fadd_rn(r[0], r[1]), __fadd_rn(r[2], r[3])),
        __fadd_rn(__fadd_rn(r[4], r[5]), __fadd_rn(r[6], r[7])));
    float best = 3.4e38f;
    int bidx = 0;
    for (int k = 0; k < KCB; k++) {
        const float4* er = (const float4*)(emb + (size_t)k * DIM);
        double s0 = 0.0, s1 = 0.0, s2 = 0.0, s3 = 0.0;
#pragma unroll
        for (int i = 0; i < 16; i++) {
            float4 e = er[i];
            s0 = fma((double)e.x, (double)xf[4 * i + 0], s0);
            s1 = fma((double)e.y, (double)xf[4 * i + 1], s1);
            s2 = fma((double)e.z, (double)xf[4 * i + 2], s2);
            s3 = fma((double)e.w, (double)xf[4 * i + 3], s3);
        }
        float dot32 = (float)((s0 + s1) + (s2 + s3));
        float t1 = __fadd_rn(sx, se[k]);
        float d = __fsub_rn(t1, __fmul_rn(2.0f, dot32));
        if (d < best) { best = d; bidx = k; }
    }
    sidx[threadIdx.x] = bidx;
    const float4* eb = (const float4*)(emb + (size_t)bidx * DIM);
    float4* oq = (float4*)(outq + (size_t)n * DIM);
    float sq = 0.0f;
#pragma unroll
    for (int i = 0; i < 16; i++) {
        float4 e = eb[i];
        float a0 = e.x - xf[4 * i + 0], a1 = e.y - xf[4 * i + 1];
        float a2 = e.z - xf[4 * i + 2], a3 = e.w - xf[4 * i + 3];
        sq += a0 * a0 + a1 * a1 + a2 * a2 + a3 * a3;
        oq[i] = e;
    }
    for (int off = 32; off; off >>= 1) sq += __shfl_down(sq, off);
    int lane = threadIdx.x & 63, w = threadIdx.x >> 6;
    if (lane == 0) red[w] = sq;
    __syncthreads();
    if (threadIdx.x == 0) atomicAdd(lossacc, red[0] + red[1] + red[2] + red[3]);
    float4* encb = (float4*)enc + (size_t)blockIdx.x * 256 * 256;
    for (int t = threadIdx.x; t < 256 * 256; t += 256) {
        int id = sidx[t >> 8];
        int j = (t & 255) << 2;
        float4 v;
        v.x = (id == j + 0) ? 1.0f : 0.0f;
        v.y = (id == j + 1) ? 1.0f : 0.0f;
        v.z = (id == j + 2) ? 1.0f : 0.0f;
        v.w = (id == j + 3) ? 1.0f : 0.0f;
        encb[t] = v;
    }
}

__global__ void vq_fin(float* __restrict__ loss3) {
    if (threadIdx.x == 0 && blockIdx.x == 0) {
        float m = loss3[1] * (1.0f / (float)((size_t)NVEC * DIM));
        loss3[0] = 1.25f * m;
        loss3[1] = m;
        loss3[2] = m;
    }
}

extern "C" void kernel_launch(void* const* d_in, const int* in_sizes, int n_in,
                              void* d_out, int out_size, void* d_ws, size_t ws_size,
                              hipStream_t stream) {
    const float* x = (const float*)d_in[0];    // [16,4096,64] f32
    const float* emb = (const float*)d_in[1];  // [1024,64] f32
    float* out = (float*)d_out;

    hipLaunchKernelGGL(vq_zero, dim3(1), dim3(64), 0, stream, out + LOSS_OFF);
    if (ws_size >= (size_t)WS_NEED) {
        double* emb64 = (double*)((char*)d_ws + WS_E64_BOFF);
        float* se = (float*)((char*)d_ws + WS_SE_BOFF);
        hipLaunchKernelGGL(vq_cvt, dim3(256), dim3(256), 0, stream, emb, emb64, se);
        hipLaunchKernelGGL(vq_main5, dim3(NVEC / 64), dim3(256), 0, stream,
                           x, emb, emb64, se, out, out + ENC_OFF, out + LOSS_OFF + 1);
    } else {
        hipLaunchKernelGGL(vq_main_fb, dim3(NVEC / 256), dim3(256), 0, stream,
                           x, emb, out, out + ENC_OFF, out + LOSS_OFF + 1);
    }
    hipLaunchKernelGGL(vq_fin, dim3(1), dim3(64), 0, stream, out + LOSS_OFF);
}

// Round 6
// 859.877 us; speedup vs baseline: 1.6031x; 1.6031x over previous
//
#include <hip/hip_runtime.h>

// N=65536 vectors (16x4096), D=64, K=1024, all fp32.
// d_out (f32 flat concat): quantized[N*D], one-hot[N*K], loss, cb_loss, commit_loss.
//
// Strategy: f32 screening pass (fast) + certified fp64 refine (rare).
// The np-f32 reference computes d = fl32(fl32(sx+se) - 2*fl32(dot)), values on
// a ~7.6e-6 grid near 64. Error budget: np-formula noise eta <= 1.7e-5
// (roundings 1.53e-5 + einsum err, |dot| <= ||x||||e|| <= 0.1), f32-screen dot
// err <= 1e-6. If screen gap(best,2nd) > B=1e-4 (2.8x the bound), the screen
// winner IS the np argmin provably. Else the row is flagged and refined with
// the R4-verified bit-exact fp64 np-formula replica (strict <, ascending k =
// first-index tie-break).
#define NVEC 65536
#define KCB  1024
#define DIM  64
#define ENC_OFF   ((size_t)NVEC * DIM)            // 4194304
#define LOSS_OFF  (ENC_OFF + (size_t)NVEC * KCB)  // 71303168
#define BAND 1e-4f

// ws layout (bytes) — 266 KB, well under the >=528 KB proven in R5:
//   [0..4)        int   flagged counter
//   [256..4352)   float se[1024]  (fl32 of exact ||e||^2)
//   [4352..266496) u32  list[65536]  packed n | (provisional_idx << 16)
#define WS_SE_BOFF   256
#define WS_LIST_BOFF 4352

__global__ void vq_prep(const float* __restrict__ emb, float* __restrict__ se,
                        int* __restrict__ counter, float* __restrict__ loss3) {
    int g = blockIdx.x * 256 + threadIdx.x;  // 1024 threads
    if (g == 0) *counter = 0;
    if (g < 3) loss3[g] = 0.0f;
    const float4* er = (const float4*)(emb + (size_t)g * DIM);
    double s0 = 0.0, s1 = 0.0, s2 = 0.0, s3 = 0.0;  // same chains as R4 (verified)
#pragma unroll
    for (int i = 0; i < 16; i++) {
        float4 e = er[i];
        s0 = fma((double)e.x, (double)e.x, s0);
        s1 = fma((double)e.y, (double)e.y, s1);
        s2 = fma((double)e.z, (double)e.z, s2);
        s3 = fma((double)e.w, (double)e.w, s3);
    }
    se[g] = (float)((s0 + s1) + (s2 + s3));
}

// Screen: block = 64 vectors x 4 code-quarters (wave q scans [256q,256q+256)).
// Pure f32 k-loop; tracks best & 2nd-best of v = se[k] - 2*dot32 (sx dropped:
// common shift per n, irrelevant for gap-based certification).
__global__ __launch_bounds__(256) void vq_screen(const float* __restrict__ x,
                                                 const float* __restrict__ emb,
                                                 const float* __restrict__ se,
                                                 int* __restrict__ counter,
                                                 unsigned* __restrict__ list,
                                                 float* __restrict__ outq,
                                                 float* __restrict__ enc,
                                                 float* __restrict__ lossacc) {
    __shared__ float sb[4][64], sb2[4][64];
    __shared__ int   si[4][64];
    __shared__ int   sidx[64];
    __shared__ float red[4];

    const int lane = threadIdx.x & 63;
    const int q = threadIdx.x >> 6;
    const int n = blockIdx.x * 64 + lane;

    const float4* xr = (const float4*)(x + (size_t)n * DIM);
    float xf[64];
#pragma unroll
    for (int i = 0; i < 16; i++) ((float4*)xf)[i] = xr[i];

    float best = 3.4e38f, best2 = 3.4e38f;
    int bidx = q * 256;
    const float4* eq = (const float4*)emb + (size_t)(q * 256) * 16;
    const float* seq = se + q * 256;
#pragma unroll 2
    for (int kk = 0; kk < 256; kk++) {
        const float4* er = eq + kk * 16;
        float d0 = 0.f, d1 = 0.f, d2 = 0.f, d3 = 0.f;  // 4 chains: ILP + err<=~5e-7
#pragma unroll
        for (int i = 0; i < 16; i++) {
            float4 e = er[i];
            d0 = fmaf(e.x, xf[4 * i + 0], d0);
            d1 = fmaf(e.y, xf[4 * i + 1], d1);
            d2 = fmaf(e.z, xf[4 * i + 2], d2);
            d3 = fmaf(e.w, xf[4 * i + 3], d3);
        }
        float dot = (d0 + d1) + (d2 + d3);
        float v = fmaf(-2.0f, dot, seq[kk]);
        if (v < best) { best2 = best; best = v; bidx = q * 256 + kk; }
        else if (v < best2) { best2 = v; }
    }
    sb[q][lane] = best; sb2[q][lane] = best2; si[q][lane] = bidx;
    __syncthreads();

    // merge quarters (ascending q); compute global best + global 2nd value
    if (threadIdx.x < 64) {
        float g1 = sb[0][lane], g2 = sb2[0][lane];
        int gi = si[0][lane];
#pragma unroll
        for (int qq = 1; qq < 4; qq++) {
            float b = sb[qq][lane], b2 = sb2[qq][lane];
            if (b < g1) { g2 = fminf(g1, b2); g1 = b; gi = si[qq][lane]; }
            else        { g2 = fminf(g2, b); }
        }
        sidx[lane] = gi;
        if (g2 - g1 < BAND) {  // uncertain -> flag for exact refine
            int pos = atomicAdd(counter, 1);
            list[pos] = (unsigned)(blockIdx.x * 64 + lane) | ((unsigned)gi << 16);
        }
    }
    __syncthreads();

    // provisional epilogue: quantized write + loss partials (R5-proven mapping)
    {
        int vec = threadIdx.x >> 2, ch = threadIdx.x & 3;
        int id = sidx[vec];
        const float4* ebp = (const float4*)(emb + (size_t)id * DIM) + ch * 4;
        const float4* xp = (const float4*)(x + (size_t)(blockIdx.x * 64 + vec) * DIM) + ch * 4;
        float4* op = (float4*)(outq + (size_t)(blockIdx.x * 64 + vec) * DIM) + ch * 4;
        float sq = 0.0f;
#pragma unroll
        for (int i = 0; i < 4; i++) {
            float4 e = ebp[i];
            float4 xv = xp[i];
            float a0 = e.x - xv.x, a1 = e.y - xv.y;
            float a2 = e.z - xv.z, a3 = e.w - xv.w;
            sq += a0 * a0 + a1 * a1 + a2 * a2 + a3 * a3;
            op[i] = e;
        }
        for (int off = 32; off; off >>= 1) sq += __shfl_down(sq, off);
        if ((threadIdx.x & 63) == 0) red[threadIdx.x >> 6] = sq;
        __syncthreads();
        if (threadIdx.x == 0) atomicAdd(lossacc, red[0] + red[1] + red[2] + red[3]);
    }

    // provisional one-hot slab: 64 rows x 256 float4, coalesced
    float4* encb = (float4*)enc + (size_t)blockIdx.x * 64 * 256;
    for (int t = threadIdx.x; t < 64 * 256; t += 256) {
        int id = sidx[t >> 8];
        int j = (t & 255) << 2;
        float4 v;
        v.x = (id == j + 0) ? 1.0f : 0.0f;
        v.y = (id == j + 1) ? 1.0f : 0.0f;
        v.z = (id == j + 2) ? 1.0f : 0.0f;
        v.w = (id == j + 3) ? 1.0f : 0.0f;
        encb[t] = v;
    }
}

// Refine: fixed grid, wave-per-flagged-row work stealing. Recomputes the
// EXACT np-f32 formula (verbatim R4-verified arithmetic) over all 1024 codes
// (16 codes per lane), lexicographic (d,k) reduce = np first-index tie-break.
__global__ __launch_bounds__(256) void vq_refine(const float* __restrict__ x,
                                                 const float* __restrict__ emb,
                                                 const float* __restrict__ se,
                                                 const int* __restrict__ counter,
                                                 const unsigned* __restrict__ list,
                                                 float* __restrict__ outq,
                                                 float* __restrict__ enc,
                                                 float* __restrict__ lossacc) {
    const int cnt = *counter;
    const int lane = threadIdx.x & 63;
    const int gw = blockIdx.x * 4 + (threadIdx.x >> 6);

    for (int it = gw; it < cnt; it += 256 * 4) {
        unsigned ent = list[it];
        int n = (int)(ent & 0xFFFFu);
        int oldi = (int)(ent >> 16);

        const float4* xr = (const float4*)(x + (size_t)n * DIM);
        float xf[64];
#pragma unroll
        for (int i = 0; i < 16; i++) ((float4*)xf)[i] = xr[i];

        // sx = numpy pairwise tree (verbatim R4; rounding is load-bearing)
        float r[8];
#pragma unroll
        for (int j = 0; j < 8; j++) r[j] = __fmul_rn(xf[j], xf[j]);
#pragma unroll
        for (int b = 1; b < 8; b++)
#pragma unroll
            for (int j = 0; j < 8; j++)
                r[j] = __fadd_rn(r[j], __fmul_rn(xf[8 * b + j], xf[8 * b + j]));
        float sx = __fadd_rn(
            __fadd_rn(__fadd_rn(r[0], r[1]), __fadd_rn(r[2], r[3])),
            __fadd_rn(__fadd_rn(r[4], r[5]), __fadd_rn(r[6], r[7])));

        float bd = 3.4e38f;
        int bk = lane * 16;
        for (int c = 0; c < 16; c++) {
            int k = lane * 16 + c;
            const float4* er = (const float4*)(emb + (size_t)k * DIM);
            double s0 = 0.0, s1 = 0.0, s2 = 0.0, s3 = 0.0;  // verbatim R4 chains
#pragma unroll
            for (int i = 0; i < 16; i++) {
                float4 e = er[i];
                s0 = fma((double)e.x, (double)xf[4 * i + 0], s0);
                s1 = fma((double)e.y, (double)xf[4 * i + 1], s1);
                s2 = fma((double)e.z, (double)xf[4 * i + 2], s2);
                s3 = fma((double)e.w, (double)xf[4 * i + 3], s3);
            }
            float dot32 = (float)((s0 + s1) + (s2 + s3));
            float t1 = __fadd_rn(sx, se[k]);
            float d = __fsub_rn(t1, __fmul_rn(2.0f, dot32));
            if (d < bd) { bd = d; bk = k; }  // strict <, ascending k
        }
        // lexicographic (d, k) wave reduce -> global min with first-index ties
        for (int off = 32; off; off >>= 1) {
            float od = __shfl_down(bd, off);
            int ok = __shfl_down(bk, off);
            if (od < bd || (od == bd && ok < bk)) { bd = od; bk = ok; }
        }
        if (lane == 0 && bk != oldi) {
            enc[(size_t)n * KCB + oldi] = 0.0f;
            enc[(size_t)n * KCB + bk] = 1.0f;
            const float4* en = (const float4*)(emb + (size_t)bk * DIM);
            const float4* eo = (const float4*)(emb + (size_t)oldi * DIM);
            float4* oq = (float4*)(outq + (size_t)n * DIM);
            float dsq = 0.0f;
#pragma unroll
            for (int i = 0; i < 16; i++) {
                float4 a = en[i], b = eo[i];
                float4 xv = ((float4*)xf)[i];
                float n0 = a.x - xv.x, n1 = a.y - xv.y, n2 = a.z - xv.z, n3 = a.w - xv.w;
                float o0 = b.x - xv.x, o1 = b.y - xv.y, o2 = b.z - xv.z, o3 = b.w - xv.w;
                dsq += (n0 * n0 + n1 * n1 + n2 * n2 + n3 * n3)
                     - (o0 * o0 + o1 * o1 + o2 * o2 + o3 * o3);
                oq[i] = a;
            }
            atomicAdd(lossacc, dsq);
        }
    }
}

__global__ void vq_fin(float* __restrict__ loss3) {
    if (threadIdx.x == 0 && blockIdx.x == 0) {
        float m = loss3[1] * (1.0f / (float)((size_t)NVEC * DIM));
        loss3[0] = 1.25f * m;  // loss = cb + 0.25*commit (values identical)
        loss3[1] = m;
        loss3[2] = m;
    }
}

extern "C" void kernel_launch(void* const* d_in, const int* in_sizes, int n_in,
                              void* d_out, int out_size, void* d_ws, size_t ws_size,
                              hipStream_t stream) {
    const float* x = (const float*)d_in[0];    // [16,4096,64] f32
    const float* emb = (const float*)d_in[1];  // [1024,64] f32
    float* out = (float*)d_out;
    int* counter = (int*)d_ws;
    float* se = (float*)((char*)d_ws + WS_SE_BOFF);
    unsigned* list = (unsigned*)((char*)d_ws + WS_LIST_BOFF);

    hipLaunchKernelGGL(vq_prep, dim3(4), dim3(256), 0, stream,
                       emb, se, counter, out + LOSS_OFF);
    hipLaunchKernelGGL(vq_screen, dim3(NVEC / 64), dim3(256), 0, stream,
                       x, emb, se, counter, list, out, out + ENC_OFF, out + LOSS_OFF + 1);
    hipLaunchKernelGGL(vq_refine, dim3(256), dim3(256), 0, stream,
                       x, emb, se, counter, list, out, out + ENC_OFF, out + LOSS_OFF + 1);
    hipLaunchKernelGGL(vq_fin, dim3(1), dim3(64), 0, stream, out + LOSS_OFF);
}

// Round 7
// 439.974 us; speedup vs baseline: 3.1330x; 1.9544x over previous
//
#include <hip/hip_runtime.h>
#include <float.h>

// N=65536 vectors (16x4096), D=64, K=1024, all fp32.
// d_out (f32 flat concat): quantized[N*D], one-hot[N*K], loss, cb_loss, commit_loss.
//
// Screen = bf16-split MFMA GEMM (hh+hl+lh, dot err <= ~5e-6) tracking
// (best, 2nd-best, idx) per row. If gap >= BAND=6e-5 (> 2*eta(np,1.6e-5) +
// 2*eps(screen)), the screen winner provably equals the np-f32 argmin.
// Else row is flagged and re-done with the R4-verified bit-exact np replica.
#define NVEC 65536
#define KCB  1024
#define DIM  64
#define ENC_OFF   ((size_t)NVEC * DIM)
#define LOSS_OFF  (ENC_OFF + (size_t)NVEC * KCB)
#define BAND 6e-5f

// ws layout (bytes), total 462912 <= 528384 proven available in R5:
#define WS_SE_BOFF   64                              // float se[1024]
#define WS_LIST_BOFF 4160                            // u32 list[LIST_CAP]
#define LIST_CAP     49152
#define WS_EH_BOFF   (WS_LIST_BOFF + LIST_CAP * 4)   // ushort eh[1024*64]
#define WS_EL_BOFF   (WS_EH_BOFF + 131072)           // ushort el[1024*64]

typedef __attribute__((ext_vector_type(8))) short short8;
typedef __attribute__((ext_vector_type(4))) float f32x4;
typedef __attribute__((ext_vector_type(4))) unsigned int u32x4;

__device__ __forceinline__ unsigned short f2bf(float f) {
    unsigned u = __float_as_uint(f);
    return (unsigned short)((u + 0x7FFFu + ((u >> 16) & 1u)) >> 16);  // RNE
}
__device__ __forceinline__ float bf2f(unsigned short h) {
    return __uint_as_float((unsigned)h << 16);
}

// prep: counter/loss zero, bit-path se[k] (fp64-exact -> fl32, verbatim R4),
// and bf16 hi/lo split of the codebook.
__global__ __launch_bounds__(256) void vq_prep(const float* __restrict__ emb,
                                               float* __restrict__ se,
                                               int* __restrict__ counter,
                                               unsigned short* __restrict__ eh,
                                               unsigned short* __restrict__ el,
                                               float* __restrict__ loss3) {
    int g = blockIdx.x * 256 + threadIdx.x;  // 1024 threads
    if (g == 0) *counter = 0;
    if (g < 3) loss3[g] = 0.0f;
    {
        const f32x4* er = (const f32x4*)(emb + (size_t)g * DIM);
        double s0 = 0.0, s1 = 0.0, s2 = 0.0, s3 = 0.0;
#pragma unroll
        for (int i = 0; i < 16; i++) {
            f32x4 e = er[i];
            s0 = fma((double)e.x, (double)e.x, s0);
            s1 = fma((double)e.y, (double)e.y, s1);
            s2 = fma((double)e.z, (double)e.z, s2);
            s3 = fma((double)e.w, (double)e.w, s3);
        }
        se[g] = (float)((s0 + s1) + (s2 + s3));
    }
    for (int i = g; i < KCB * DIM; i += 1024) {
        float v = emb[i];
        unsigned short h = f2bf(v);
        eh[i] = h;
        el[i] = f2bf(v - bf2f(h));
    }
}

// Screen: block = 64 vectors (4 waves x 16), full K=1024 per block.
// E (bf16 hi/lo) staged per 256-code super-tile in LDS (144B padded rows).
// 16x16x32 bf16 MFMA, verified layouts: A[m=lane&15][k=quad*8+j];
// D: col(lane&15)=code, rows(quad*4+reg)=4 vectors.
__global__ __launch_bounds__(256) void vq_screen(const float* __restrict__ x,
                                                 const float* __restrict__ emb,
                                                 const float* __restrict__ se,
                                                 const unsigned short* __restrict__ eh,
                                                 const unsigned short* __restrict__ el,
                                                 int* __restrict__ counter,
                                                 unsigned* __restrict__ list,
                                                 float* __restrict__ outq,
                                                 float* __restrict__ enc,
                                                 float* __restrict__ lossacc) {
    __shared__ unsigned short sEh[256 * 72];  // 36 KB, 72-short (144B) rows
    __shared__ unsigned short sEl[256 * 72];  // 36 KB
    __shared__ float sse[KCB];                // 4 KB
    __shared__ int sidx[64];
    __shared__ float red[4];

    const int tid = threadIdx.x;
    const int wave = tid >> 6, lane = tid & 63;
    const int q = lane >> 4, c = lane & 15;

    for (int t = tid; t < KCB; t += 256) sse[t] = se[t];

    // a-frags: this wave's 16 vectors, lane's row m = c, d-chunk = q*8+j.
    const int vecm = blockIdx.x * 64 + wave * 16 + c;
    float xa[16];
    {
        const f32x4* xp = (const f32x4*)(x + (size_t)vecm * DIM);
        ((f32x4*)xa)[0] = xp[2 * q];
        ((f32x4*)xa)[1] = xp[2 * q + 1];
        ((f32x4*)xa)[2] = xp[8 + 2 * q];
        ((f32x4*)xa)[3] = xp[8 + 2 * q + 1];
    }
    short8 ah0, al0, ah1, al1;
#pragma unroll
    for (int j = 0; j < 8; j++) {
        unsigned short h0 = f2bf(xa[j]);
        ah0[j] = (short)h0;
        al0[j] = (short)f2bf(xa[j] - bf2f(h0));
        unsigned short h1 = f2bf(xa[8 + j]);
        ah1[j] = (short)h1;
        al1[j] = (short)f2bf(xa[8 + j] - bf2f(h1));
    }

    float b1[4], b2[4];
    int i1[4];
#pragma unroll
    for (int r = 0; r < 4; r++) { b1[r] = FLT_MAX; b2[r] = FLT_MAX; i1[r] = 0; }

    for (int st = 0; st < 4; st++) {
        __syncthreads();  // previous super-tile reads done
        // stage 256 codes x 64 shorts x {eh,el}: 4096 16B units, 16/thread
        for (int u = tid; u < 4096; u += 256) {
            int arr = u >> 11;
            int v = u & 2047;
            int code = v >> 3, unit = v & 7;
            const u32x4* src = (const u32x4*)((arr ? el : eh)
                                + ((size_t)(st * 256 + code) * 64 + unit * 8));
            u32x4 val = *src;
            unsigned short* dst = (arr ? sEl : sEh) + (code * 72 + unit * 8);
            *(u32x4*)dst = val;
        }
        __syncthreads();

#pragma unroll 2
        for (int t = 0; t < 16; t++) {
            int cl = t * 16 + c;  // local code row (lane's column)
            const unsigned short* bph = sEh + (cl * 72 + q * 8);
            const unsigned short* bpl = sEl + (cl * 72 + q * 8);
            short8 bh0 = *(const short8*)bph;
            short8 bh1 = *(const short8*)(bph + 32);
            short8 bl0 = *(const short8*)bpl;
            short8 bl1 = *(const short8*)(bpl + 32);
            f32x4 acc = {0.f, 0.f, 0.f, 0.f};
            acc = __builtin_amdgcn_mfma_f32_16x16x32_bf16(ah0, bh0, acc, 0, 0, 0);
            acc = __builtin_amdgcn_mfma_f32_16x16x32_bf16(ah1, bh1, acc, 0, 0, 0);
            acc = __builtin_amdgcn_mfma_f32_16x16x32_bf16(ah0, bl0, acc, 0, 0, 0);
            acc = __builtin_amdgcn_mfma_f32_16x16x32_bf16(ah1, bl1, acc, 0, 0, 0);
            acc = __builtin_amdgcn_mfma_f32_16x16x32_bf16(al0, bh0, acc, 0, 0, 0);
            acc = __builtin_amdgcn_mfma_f32_16x16x32_bf16(al1, bh1, acc, 0, 0, 0);
            int kcur = st * 256 + t * 16 + c;
            float sek = sse[kcur];
#pragma unroll
            for (int r = 0; r < 4; r++) {
                float v = fmaf(-2.f, acc[r], sek);
                bool lt = v < b1[r];
                b2[r] = fminf(fmaxf(v, b1[r]), b2[r]);  // med3(b1,b2,v), b1<=b2
                b1[r] = lt ? v : b1[r];
                i1[r] = lt ? kcur : i1[r];
            }
        }
    }

    // butterfly reduce (b1,i1,b2) across the 16 lanes of each quad
#pragma unroll
    for (int m = 1; m <= 8; m <<= 1) {
#pragma unroll
        for (int r = 0; r < 4; r++) {
            float ob1 = __shfl_xor(b1[r], m, 64);
            float ob2 = __shfl_xor(b2[r], m, 64);
            int oi = __shfl_xor(i1[r], m, 64);
            float nb2 = fminf(fmaxf(b1[r], ob1), fminf(b2[r], ob2));
            if (ob1 < b1[r]) { b1[r] = ob1; i1[r] = oi; }
            b2[r] = nb2;
        }
    }

    if (c == 0) {
#pragma unroll
        for (int r = 0; r < 4; r++) {
            int row = wave * 16 + q * 4 + r;  // D rows = quad*4+reg
            sidx[row] = i1[r];
            if (b2[r] - b1[r] < BAND) {
                int pos = atomicAdd(counter, 1);
                if (pos < LIST_CAP)
                    list[pos] = (unsigned)(blockIdx.x * 64 + row) | ((unsigned)i1[r] << 16);
            }
        }
    }
    __syncthreads();

    // provisional epilogue (R6-proven): quantized + loss, then one-hot slab
    {
        int vec = tid >> 2, ch = tid & 3;
        int id = sidx[vec];
        const f32x4* ebp = (const f32x4*)(emb + (size_t)id * DIM) + ch * 4;
        const f32x4* xp = (const f32x4*)(x + (size_t)(blockIdx.x * 64 + vec) * DIM) + ch * 4;
        f32x4* op = (f32x4*)(outq + (size_t)(blockIdx.x * 64 + vec) * DIM) + ch * 4;
        float sq = 0.0f;
#pragma unroll
        for (int i = 0; i < 4; i++) {
            f32x4 e = ebp[i];
            f32x4 xv = xp[i];
            f32x4 d = e - xv;
            sq += d.x * d.x + d.y * d.y + d.z * d.z + d.w * d.w;
            op[i] = e;
        }
        for (int off = 32; off; off >>= 1) sq += __shfl_down(sq, off);
        if ((tid & 63) == 0) red[tid >> 6] = sq;
        __syncthreads();
        if (tid == 0) atomicAdd(lossacc, red[0] + red[1] + red[2] + red[3]);
    }

    f32x4* encb = (f32x4*)enc + (size_t)blockIdx.x * 64 * 256;
    for (int t = tid; t < 64 * 256; t += 256) {
        int id = sidx[t >> 8];
        int j = (t & 255) << 2;
        f32x4 v;
        v.x = (id == j + 0) ? 1.0f : 0.0f;
        v.y = (id == j + 1) ? 1.0f : 0.0f;
        v.z = (id == j + 2) ? 1.0f : 0.0f;
        v.w = (id == j + 3) ? 1.0f : 0.0f;
        encb[t] = v;
    }
}

// Refine: verbatim R6 bit-exact np replica for flagged rows (wave/row).
__global__ __launch_bounds__(256) void vq_refine(const float* __restrict__ x,
                                                 const float* __restrict__ emb,
                                                 const float* __restrict__ se,
                                                 const int* __restrict__ counter,
                                                 const unsigned* __restrict__ list,
                                                 float* __restrict__ outq,
                                                 float* __restrict__ enc,
                                                 float* __restrict__ lossacc) {
    const int cnt = min(*counter, LIST_CAP);
    const int lane = threadIdx.x & 63;
    const int gw = blockIdx.x * 4 + (threadIdx.x >> 6);
    const int nw = gridDim.x * 4;

    for (int it = gw; it < cnt; it += nw) {
        unsigned ent = list[it];
        int n = (int)(ent & 0xFFFFu);
        int oldi = (int)(ent >> 16);

        const float4* xr = (const float4*)(x + (size_t)n * DIM);
        float xf[64];
#pragma unroll
        for (int i = 0; i < 16; i++) ((float4*)xf)[i] = xr[i];

        float r[8];
#pragma unroll
        for (int j = 0; j < 8; j++) r[j] = __fmul_rn(xf[j], xf[j]);
#pragma unroll
        for (int b = 1; b < 8; b++)
#pragma unroll
            for (int j = 0; j < 8; j++)
                r[j] = __fadd_rn(r[j], __fmul_rn(xf[8 * b + j], xf[8 * b + j]));
        float sx = __fadd_rn(
            __fadd_rn(__fadd_rn(r[0], r[1]), __fadd_rn(r[2], r[3])),
            __fadd_rn(__fadd_rn(r[4], r[5]), __fadd_rn(r[6], r[7])));

        float bd = 3.4e38f;
        int bk = lane * 16;
        for (int cc = 0; cc < 16; cc++) {
            int k = lane * 16 + cc;
            const float4* er = (const float4*)(emb + (size_t)k * DIM);
            double s0 = 0.0, s1 = 0.0, s2 = 0.0, s3 = 0.0;  // verbatim R4
#pragma unroll
            for (int i = 0; i < 16; i++) {
                float4 e = er[i];
                s0 = fma((double)e.x, (double)xf[4 * i + 0], s0);
                s1 = fma((double)e.y, (double)xf[4 * i + 1], s1);
                s2 = fma((double)e.z, (double)xf[4 * i + 2], s2);
                s3 = fma((double)e.w, (double)xf[4 * i + 3], s3);
            }
            float dot32 = (float)((s0 + s1) + (s2 + s3));
            float t1 = __fadd_rn(sx, se[k]);
            float d = __fsub_rn(t1, __fmul_rn(2.0f, dot32));
            if (d < bd) { bd = d; bk = k; }
        }
        for (int off = 32; off; off >>= 1) {
            float od = __shfl_down(bd, off);
            int ok = __shfl_down(bk, off);
            if (od < bd || (od == bd && ok < bk)) { bd = od; bk = ok; }
        }
        if (lane == 0 && bk != oldi) {
            enc[(size_t)n * KCB + oldi] = 0.0f;
            enc[(size_t)n * KCB + bk] = 1.0f;
            const float4* en = (const float4*)(emb + (size_t)bk * DIM);
            const float4* eo = (const float4*)(emb + (size_t)oldi * DIM);
            float4* oq = (float4*)(outq + (size_t)n * DIM);
            float dsq = 0.0f;
#pragma unroll
            for (int i = 0; i < 16; i++) {
                float4 a = en[i], b = eo[i];
                float4 xv = ((float4*)xf)[i];
                float n0 = a.x - xv.x, n1 = a.y - xv.y, n2 = a.z - xv.z, n3 = a.w - xv.w;
                float o0 = b.x - xv.x, o1 = b.y - xv.y, o2 = b.z - xv.z, o3 = b.w - xv.w;
                dsq += (n0 * n0 + n1 * n1 + n2 * n2 + n3 * n3)
                     - (o0 * o0 + o1 * o1 + o2 * o2 + o3 * o3);
                oq[i] = a;
            }
            atomicAdd(lossacc, dsq);
        }
    }
}

__global__ void vq_fin(float* __restrict__ loss3) {
    if (threadIdx.x == 0 && blockIdx.x == 0) {
        float m = loss3[1] * (1.0f / (float)((size_t)NVEC * DIM));
        loss3[0] = 1.25f * m;
        loss3[1] = m;
        loss3[2] = m;
    }
}

extern "C" void kernel_launch(void* const* d_in, const int* in_sizes, int n_in,
                              void* d_out, int out_size, void* d_ws, size_t ws_size,
                              hipStream_t stream) {
    const float* x = (const float*)d_in[0];
    const float* emb = (const float*)d_in[1];
    float* out = (float*)d_out;
    int* counter = (int*)d_ws;
    float* se = (float*)((char*)d_ws + WS_SE_BOFF);
    unsigned* list = (unsigned*)((char*)d_ws + WS_LIST_BOFF);
    unsigned short* eh = (unsigned short*)((char*)d_ws + WS_EH_BOFF);
    unsigned short* el = (unsigned short*)((char*)d_ws + WS_EL_BOFF);

    hipLaunchKernelGGL(vq_prep, dim3(4), dim3(256), 0, stream,
                       emb, se, counter, eh, el, out + LOSS_OFF);
    hipLaunchKernelGGL(vq_screen, dim3(NVEC / 64), dim3(256), 0, stream,
                       x, emb, se, eh, el, counter, list,
                       out, out + ENC_OFF, out + LOSS_OFF + 1);
    hipLaunchKernelGGL(vq_refine, dim3(1024), dim3(256), 0, stream,
                       x, emb, se, counter, list,
                       out, out + ENC_OFF, out + LOSS_OFF + 1);
    hipLaunchKernelGGL(vq_fin, dim3(1), dim3(64), 0, stream, out + LOSS_OFF);
}